// Round 18
// baseline (104.824 us; speedup 1.0000x reference)
//
#include <hip/hip_runtime.h>

// Window attention, bf16-MFMA (R18): R16 body EXACTLY (best structure, 89.9us)
// + R17's dual-pattern swizzle ONLY (proven: conflicts 5.77M->3.67M).
// R17's bias-in-accumulator is REVERTED (it put scalar bias loads on the
// critical path before each pass's first MFMA: 89.9->98 regression).
//  - swizzle mask m(tok)=(tok&3)|(((tok>>2)^(tok>>3))&1)<<2: conflict-free
//    for natural rows (Q/proj/ao) AND sigma-permuted K/V rows.
//  - K+V merged pass, proj aof hoisted, fragment-major weights (R15/R16).

typedef __attribute__((ext_vector_type(8))) short bf16x8;
typedef __attribute__((ext_vector_type(4))) float f32x4;
typedef __attribute__((ext_vector_type(4))) __bf16 bf16x4;

#define MFMA32(a, b, c) __builtin_amdgcn_mfma_f32_16x16x32_bf16(a, b, c, 0, 0, 0)

__device__ __forceinline__ uint2 pack4bf(float a, float b, float c, float d) {
    bf16x4 v; v[0] = (__bf16)a; v[1] = (__bf16)b; v[2] = (__bf16)c; v[3] = (__bf16)d;
    union { bf16x4 v; uint2 u; } pun; pun.v = v; return pun.u;
}

__device__ __forceinline__ bf16x8 cat8(uint2 lo, uint2 hi) {
    union { uint4 u; bf16x8 v; } p;
    p.u.x = lo.x; p.u.y = lo.y; p.u.z = hi.x; p.u.w = hi.y;
    return p.v;
}

// Swizzled [64][128] bf16 tile offset (row 256B). Mask spans 8 values evenly
// for natural rows (16t+cn) AND sigma rows (32a+8e+4b+c) -> no LDS conflicts.
__device__ __forceinline__ int ao_off(int tok, int c) {
    const int m = (tok & 3) | ((((tok >> 2) ^ (tok >> 3)) & 1) << 2);
    return (tok << 7) + ((((c >> 3) & 15) ^ m) << 3) + (c & 7);
}

// ---- prep: weights FRAGMENT-MAJOR bf16 (d-permute folded for q/k);
//      bias nk sigma-permuted (identical to R16) ----
__global__ void prep_kernel(const float* __restrict__ qkv_w,
                            const float* __restrict__ proj_w,
                            const float* __restrict__ bias_table,
                            ushort* __restrict__ wq_bf,
                            ushort* __restrict__ wp_bf,
                            ushort* __restrict__ biasb) {
    int i = blockIdx.x * 256 + threadIdx.x;
    if (i < 49152) {
        // idx bits: e0-2 g3-4 cn5-8 kc9-10 ii11 hh12-13 t14+
        int e = i & 7, g = (i >> 3) & 3, cn = (i >> 5) & 15, kc = (i >> 9) & 3;
        int ii = (i >> 11) & 1, hh = (i >> 12) & 3, t = i >> 14;
        int col = 32 * kc + 8 * g + e;
        int row;
        if (t < 2)  // q,k: fragment slot cn holds d-permuted row 8*(cn>>2)+4*ii+(cn&3)
            row = t * 128 + hh * 32 + 8 * (cn >> 2) + 4 * ii + (cn & 3);
        else        // v: identity
            row = 256 + hh * 32 + 16 * ii + cn;
        union { __bf16 b; ushort s; } u; u.b = (__bf16)qkv_w[row * 128 + col];
        wq_bf[i] = u.s;
    }
    if (i < 16384) {
        // proj: idx bits e0-2 g3-4 cn5-8 kc9-10 j11-13 (j = 2h+i_half)
        int e = i & 7, g = (i >> 3) & 3, cn = (i >> 5) & 15, kc = (i >> 9) & 3, j = (i >> 11) & 7;
        union { __bf16 b; ushort s; } u;
        u.b = (__bf16)proj_w[(16 * j + cn) * 128 + 32 * kc + 8 * g + e];
        wp_bf[i] = u.s;
        // biasb[((h*64+nq)*4+g)*16 + ti*4 + r]; slot (ti,g,r) holds actual
        // k-token nk = 32*(ti>>1) + 8g + 4*(ti&1) + r   (sigma permutation)
        int h = i >> 12, nq = (i >> 6) & 63, gb = (i >> 4) & 3, ti = (i >> 2) & 3, r = i & 3;
        int nk = 32 * (ti >> 1) + 8 * gb + 4 * (ti & 1) + r;
        int idx = ((nq >> 3) - (nk >> 3) + 7) * 15 + ((nq & 7) - (nk & 7) + 7);
        union { __bf16 b; ushort s; } ub;
        ub.b = (__bf16)(bias_table[idx * 4 + h] * 1.4426950408889634f);
        biasb[i] = ub.s;
    }
}

__global__ __launch_bounds__(256, 3)
void winattn_mfma(const float* __restrict__ x,
                  const float* __restrict__ qkv_b,
                  const float* __restrict__ proj_b,
                  const ushort* __restrict__ wq_bf,
                  const ushort* __restrict__ wp_bf,
                  const ushort* __restrict__ biasb,
                  float* __restrict__ out) {
    __shared__ ushort S[16384];    // 32KB: xs [0,8192) | ao [8192,16384)

    const int tid = threadIdx.x;
    const size_t w = blockIdx.x;
    const int h  = __builtin_amdgcn_readfirstlane(tid >> 6);  // wave = head
    const int l  = tid & 63;
    const int g  = (l >> 4) & 3;   // 0..3
    const int cn = l & 15;         // 0..15

    ushort* xs  = S;
    ushort* aoL = S + 8192;
    const f32x4 zero = (f32x4){0.f, 0.f, 0.f, 0.f};
    const int lane32 = cn * 32 + g * 8;   // fragment-major lane offset (ushorts)

    // ---- stage A: x -> bf16 LDS tile ----
    const float* xg = x + w * 8192;
    #pragma unroll
    for (int it = 0; it < 8; ++it) {
        int f4 = tid + 256 * it;
        int n = f4 >> 5, c4 = f4 & 31;
        float4 xv = ((const float4*)xg)[f4];
        *(uint2*)&xs[ao_off(n, 4 * c4)] = pack4bf(xv.x, xv.y, xv.z, xv.w);
    }
    __syncthreads();                              // (1) xs ready

    bf16x8 qb[4], kb[4], vA[2][2];

    // ---- QKV pass 1: Q ----
    {
        f32x4 aq[2][4];
        #pragma unroll
        for (int i = 0; i < 2; ++i)
            #pragma unroll
            for (int tn = 0; tn < 4; ++tn) aq[i][tn] = zero;
        #pragma unroll
        for (int kc = 0; kc < 4; ++kc) {
            bf16x8 xq[4];
            #pragma unroll
            for (int tn = 0; tn < 4; ++tn)
                xq[tn] = *(const bf16x8*)&xs[ao_off(16 * tn + cn, 8 * g + 32 * kc)];
            #pragma unroll
            for (int i = 0; i < 2; ++i) {
                const bf16x8 wq = *(const bf16x8*)&wq_bf[(h * 2 + i) * 2048 + kc * 512 + lane32];
                #pragma unroll
                for (int tn = 0; tn < 4; ++tn)
                    aq[i][tn] = MFMA32(wq, xq[tn], aq[i][tn]);   // D[d'][tok]
            }
        }
        const float4 b0 = *(const float4*)&qkv_b[32 * h + 8 * g];      // i=0 (d-permuted)
        const float4 b1 = *(const float4*)&qkv_b[32 * h + 8 * g + 4];  // i=1
        #pragma unroll
        for (int tn = 0; tn < 4; ++tn) {
            f32x4 q0 = aq[0][tn], q1 = aq[1][tn];
            qb[tn] = cat8(pack4bf(q0[0] + b0.x, q0[1] + b0.y, q0[2] + b0.z, q0[3] + b0.w),
                          pack4bf(q1[0] + b1.x, q1[1] + b1.y, q1[2] + b1.z, q1[3] + b1.w));
        }
    }

    // ---- QKV pass 2: K + V MERGED (sigma-permuted x rows read ONCE) ----
    {
        f32x4 ak[2][4], av[4][2];
        #pragma unroll
        for (int i = 0; i < 2; ++i)
            #pragma unroll
            for (int tn = 0; tn < 4; ++tn) { ak[i][tn] = zero; av[tn][i] = zero; }
        #pragma unroll
        for (int kc = 0; kc < 4; ++kc) {
            bf16x8 xkv[4];
            #pragma unroll
            for (int tn = 0; tn < 4; ++tn) {
                const int row = 32 * (tn >> 1) + 8 * (cn >> 2) + 4 * (tn & 1) + (cn & 3);
                xkv[tn] = *(const bf16x8*)&xs[ao_off(row, 8 * g + 32 * kc)];
            }
            #pragma unroll
            for (int i = 0; i < 2; ++i) {
                const bf16x8 wk = *(const bf16x8*)&wq_bf[16384 + (h * 2 + i) * 2048 + kc * 512 + lane32];
                const bf16x8 wv = *(const bf16x8*)&wq_bf[32768 + (h * 2 + i) * 2048 + kc * 512 + lane32];
                #pragma unroll
                for (int tn = 0; tn < 4; ++tn) {
                    ak[i][tn] = MFMA32(wk, xkv[tn], ak[i][tn]);   // D[d'][tok-slot]
                    av[tn][i] = MFMA32(xkv[tn], wv, av[tn][i]);   // D[tok-slot][d]
                }
            }
        }
        const float4 b0 = *(const float4*)&qkv_b[128 + 32 * h + 8 * g];
        const float4 b1 = *(const float4*)&qkv_b[128 + 32 * h + 8 * g + 4];
        #pragma unroll
        for (int tn = 0; tn < 4; ++tn) {
            f32x4 k0 = ak[0][tn], k1 = ak[1][tn];
            kb[tn] = cat8(pack4bf(k0[0] + b0.x, k0[1] + b0.y, k0[2] + b0.z, k0[3] + b0.w),
                          pack4bf(k1[0] + b1.x, k1[1] + b1.y, k1[2] + b1.z, k1[3] + b1.w));
        }
        uint2 vb2[4][2];
        #pragma unroll
        for (int i = 0; i < 2; ++i) {
            const float bv = qkv_b[256 + 32 * h + 16 * i + cn];
            #pragma unroll
            for (int tn = 0; tn < 4; ++tn) {
                f32x4 v4 = av[tn][i];
                vb2[tn][i] = pack4bf(v4[0] + bv, v4[1] + bv, v4[2] + bv, v4[3] + bv);
            }
        }
        #pragma unroll
        for (int kk = 0; kk < 2; ++kk)
            #pragma unroll
            for (int ta = 0; ta < 2; ++ta)
                vA[kk][ta] = cat8(vb2[2 * kk][ta], vb2[2 * kk + 1][ta]);
    }

    // ---- attention per tj: QK^T -> softmax -> PV (minimal live set) ----
    const float SCALE2 = 0.17677669529663687f * 1.4426950408889634f;  // scale*log2(e)
    #pragma unroll
    for (int tj = 0; tj < 4; ++tj) {
        f32x4 s[4];
        #pragma unroll
        for (int ti = 0; ti < 4; ++ti)
            s[ti] = MFMA32(kb[ti], qb[tj], zero);          // S D[slot][nq], K=32 over d

        const int nq = 16 * tj + cn;
        const ushort* bp = biasb + (((h * 64 + nq) * 4 + g) << 4);
        const uint4 bb0 = *(const uint4*)bp;
        const uint4 bb1 = *(const uint4*)(bp + 8);

        float sum = 0.f;
        uint2 pkt[4];
        #pragma unroll
        for (int ti = 0; ti < 4; ++ti) {
            const uint4 q4 = (ti < 2) ? bb0 : bb1;
            const unsigned w0 = (ti & 1) ? q4.z : q4.x;
            const unsigned w1 = (ti & 1) ? q4.w : q4.y;
            const float b0 = __uint_as_float(w0 << 16);
            const float b1 = __uint_as_float(w0 & 0xffff0000u);
            const float b2 = __uint_as_float(w1 << 16);
            const float b3 = __uint_as_float(w1 & 0xffff0000u);
            f32x4 sv = s[ti];
            sv[0] = exp2f(fmaf(sv[0], SCALE2, b0));
            sv[1] = exp2f(fmaf(sv[1], SCALE2, b1));
            sv[2] = exp2f(fmaf(sv[2], SCALE2, b2));
            sv[3] = exp2f(fmaf(sv[3], SCALE2, b3));
            pkt[ti] = pack4bf(sv[0], sv[1], sv[2], sv[3]);   // = PV B-frag piece
            sum += (sv[0] + sv[1]) + (sv[2] + sv[3]);
        }
        sum += __shfl_xor(sum, 16, 64);
        sum += __shfl_xor(sum, 32, 64);
        const float rs = 1.0f / sum;                         // lane-local

        const bf16x8 p0 = cat8(pkt[0], pkt[1]);   // B-frag, tokens 0..31
        const bf16x8 p1 = cat8(pkt[2], pkt[3]);   // B-frag, tokens 32..63
        #pragma unroll
        for (int ta = 0; ta < 2; ++ta) {
            f32x4 o = MFMA32(vA[0][ta], p0, zero);
            o = MFMA32(vA[1][ta], p1, o);                    // D[d][nq]
            *(uint2*)&aoL[ao_off(16 * tj + cn, 32 * h + 16 * ta + 4 * g)] =
                pack4bf(o[0] * rs, o[1] * rs, o[2] * rs, o[3] * rs);
        }
    }
    __syncthreads();                              // (2) ao ready

    // ---- out projection: aof read ONCE per kc (hoisted out of i-loop) ----
    float* og = out + w * 8192;
    {
        f32x4 po[2][4];
        #pragma unroll
        for (int i = 0; i < 2; ++i)
            #pragma unroll
            for (int tj = 0; tj < 4; ++tj) po[i][tj] = zero;
        #pragma unroll
        for (int kc = 0; kc < 4; ++kc) {
            bf16x8 aof[4];
            #pragma unroll
            for (int tj = 0; tj < 4; ++tj)
                aof[tj] = *(const bf16x8*)&aoL[ao_off(16 * tj + cn, 8 * g + 32 * kc)];
            #pragma unroll
            for (int i = 0; i < 2; ++i) {
                const bf16x8 pf = *(const bf16x8*)&wp_bf[(2 * h + i) * 2048 + kc * 512 + lane32];
                #pragma unroll
                for (int tj = 0; tj < 4; ++tj)
                    po[i][tj] = MFMA32(pf, aof[tj], po[i][tj]);
            }
        }
        #pragma unroll
        for (int i = 0; i < 2; ++i) {
            const int co0 = 16 * (2 * h + i) + 4 * g;
            const float4 pb4 = *(const float4*)&proj_b[co0];
            #pragma unroll
            for (int tj = 0; tj < 4; ++tj) {
                f32x4 pv = po[i][tj];
                float4 ov;
                ov.x = pv[0] + pb4.x; ov.y = pv[1] + pb4.y;
                ov.z = pv[2] + pb4.z; ov.w = pv[3] + pb4.w;
                *(float4*)&og[(16 * tj + cn) * 128 + co0] = ov;
            }
        }
    }
}

extern "C" void kernel_launch(void* const* d_in, const int* in_sizes, int n_in,
                              void* d_out, int out_size, void* d_ws, size_t ws_size,
                              hipStream_t stream) {
    const float* x          = (const float*)d_in[0];
    const float* qkv_w      = (const float*)d_in[1];
    const float* qkv_b      = (const float*)d_in[2];
    const float* proj_w     = (const float*)d_in[3];
    const float* proj_b     = (const float*)d_in[4];
    const float* bias_table = (const float*)d_in[5];
    float* out = (float*)d_out;

    // ws layout: [0,98304) wq_bf fragment-major | [98304,131072) wp_bf fragment-major
    //            [131072,163840) biasb bf16 (nk sigma-permuted)
    ushort* wq_bf = (ushort*)d_ws;
    ushort* wp_bf = (ushort*)((char*)d_ws + 98304);
    ushort* biasb = (ushort*)((char*)d_ws + 131072);

    prep_kernel<<<dim3(192), dim3(256), 0, stream>>>(qkv_w, proj_w, bias_table, wq_bf, wp_bf, biasb);
    winattn_mfma<<<dim3(4096), dim3(256), 0, stream>>>(x, qkv_b, proj_b, wq_bf, wp_bf, biasb, out);
}

// Round 19
// 85.259 us; speedup vs baseline: 1.2295x; 1.2295x over previous
//
#include <hip/hip_runtime.h>

// Window attention, bf16-MFMA (R19): R16 body EXACTLY (best, 89.9us; R17/R18's
// swizzle+bias experiments both reverted) + three PURE LOAD HOISTS (same math,
// same addresses, just issued earlier so L2 latency drains under existing
// waits):
//   1. Q-pass weight frags issued during stage A (before barrier 1)
//   2. all-tj bias loads hoisted above the attention loop
//   3. proj weight frags issued before barrier 2 (independent of ao)

typedef __attribute__((ext_vector_type(8))) short bf16x8;
typedef __attribute__((ext_vector_type(4))) float f32x4;
typedef __attribute__((ext_vector_type(4))) __bf16 bf16x4;

#define MFMA32(a, b, c) __builtin_amdgcn_mfma_f32_16x16x32_bf16(a, b, c, 0, 0, 0)

__device__ __forceinline__ uint2 pack4bf(float a, float b, float c, float d) {
    bf16x4 v; v[0] = (__bf16)a; v[1] = (__bf16)b; v[2] = (__bf16)c; v[3] = (__bf16)d;
    union { bf16x4 v; uint2 u; } pun; pun.v = v; return pun.u;
}

__device__ __forceinline__ bf16x8 cat8(uint2 lo, uint2 hi) {
    union { uint4 u; bf16x8 v; } p;
    p.u.x = lo.x; p.u.y = lo.y; p.u.z = hi.x; p.u.w = hi.y;
    return p.v;
}

// Swizzled [64][128] bf16 tile offset (row 256B). R16's mask (tok&7):
// tn-invariant for natural rows -> hoistable address math (R18 lesson).
__device__ __forceinline__ int ao_off(int tok, int c) {
    return (tok << 7) + (((((c >> 3) & 15) ^ (tok & 7)) << 3)) + (c & 7);
}

// ---- prep: weights FRAGMENT-MAJOR bf16 (d-permute folded for q/k);
//      bias nk sigma-permuted (identical to R16) ----
__global__ void prep_kernel(const float* __restrict__ qkv_w,
                            const float* __restrict__ proj_w,
                            const float* __restrict__ bias_table,
                            ushort* __restrict__ wq_bf,
                            ushort* __restrict__ wp_bf,
                            ushort* __restrict__ biasb) {
    int i = blockIdx.x * 256 + threadIdx.x;
    if (i < 49152) {
        // idx bits: e0-2 g3-4 cn5-8 kc9-10 ii11 hh12-13 t14+
        int e = i & 7, g = (i >> 3) & 3, cn = (i >> 5) & 15, kc = (i >> 9) & 3;
        int ii = (i >> 11) & 1, hh = (i >> 12) & 3, t = i >> 14;
        int col = 32 * kc + 8 * g + e;
        int row;
        if (t < 2)  // q,k: fragment slot cn holds d-permuted row 8*(cn>>2)+4*ii+(cn&3)
            row = t * 128 + hh * 32 + 8 * (cn >> 2) + 4 * ii + (cn & 3);
        else        // v: identity
            row = 256 + hh * 32 + 16 * ii + cn;
        union { __bf16 b; ushort s; } u; u.b = (__bf16)qkv_w[row * 128 + col];
        wq_bf[i] = u.s;
    }
    if (i < 16384) {
        // proj: idx bits e0-2 g3-4 cn5-8 kc9-10 j11-13 (j = 2h+i_half)
        int e = i & 7, g = (i >> 3) & 3, cn = (i >> 5) & 15, kc = (i >> 9) & 3, j = (i >> 11) & 7;
        union { __bf16 b; ushort s; } u;
        u.b = (__bf16)proj_w[(16 * j + cn) * 128 + 32 * kc + 8 * g + e];
        wp_bf[i] = u.s;
        // biasb[((h*64+nq)*4+g)*16 + ti*4 + r]; slot (ti,g,r) holds actual
        // k-token nk = 32*(ti>>1) + 8g + 4*(ti&1) + r   (sigma permutation)
        int h = i >> 12, nq = (i >> 6) & 63, gb = (i >> 4) & 3, ti = (i >> 2) & 3, r = i & 3;
        int nk = 32 * (ti >> 1) + 8 * gb + 4 * (ti & 1) + r;
        int idx = ((nq >> 3) - (nk >> 3) + 7) * 15 + ((nq & 7) - (nk & 7) + 7);
        union { __bf16 b; ushort s; } ub;
        ub.b = (__bf16)(bias_table[idx * 4 + h] * 1.4426950408889634f);
        biasb[i] = ub.s;
    }
}

__global__ __launch_bounds__(256, 3)
void winattn_mfma(const float* __restrict__ x,
                  const float* __restrict__ qkv_b,
                  const float* __restrict__ proj_b,
                  const ushort* __restrict__ wq_bf,
                  const ushort* __restrict__ wp_bf,
                  const ushort* __restrict__ biasb,
                  float* __restrict__ out) {
    __shared__ ushort S[16384];    // 32KB: xs [0,8192) | ao [8192,16384)

    const int tid = threadIdx.x;
    const size_t w = blockIdx.x;
    const int h  = __builtin_amdgcn_readfirstlane(tid >> 6);  // wave = head
    const int l  = tid & 63;
    const int g  = (l >> 4) & 3;   // 0..3
    const int cn = l & 15;         // 0..15

    ushort* xs  = S;
    ushort* aoL = S + 8192;
    const f32x4 zero = (f32x4){0.f, 0.f, 0.f, 0.f};
    const int lane32 = cn * 32 + g * 8;   // fragment-major lane offset (ushorts)

    // ---- stage A: x -> bf16 LDS tile, with Q-pass weight frags issued early ----
    const float* xg = x + w * 8192;
    float4 xv[8];
    #pragma unroll
    for (int it = 0; it < 8; ++it)
        xv[it] = ((const float4*)xg)[tid + 256 * it];

    // HOIST 1: Q-pass weight fragments (independent of xs/barrier)
    bf16x8 wqf[2][4];
    #pragma unroll
    for (int i = 0; i < 2; ++i)
        #pragma unroll
        for (int kc = 0; kc < 4; ++kc)
            wqf[i][kc] = *(const bf16x8*)&wq_bf[(h * 2 + i) * 2048 + kc * 512 + lane32];

    #pragma unroll
    for (int it = 0; it < 8; ++it) {
        int f4 = tid + 256 * it;
        int n = f4 >> 5, c4 = f4 & 31;
        *(uint2*)&xs[ao_off(n, 4 * c4)] = pack4bf(xv[it].x, xv[it].y, xv[it].z, xv[it].w);
    }
    __syncthreads();                              // (1) xs ready (wqf drained here too)

    bf16x8 qb[4], kb[4], vA[2][2];

    // ---- QKV pass 1: Q (weights already in regs) ----
    {
        f32x4 aq[2][4];
        #pragma unroll
        for (int i = 0; i < 2; ++i)
            #pragma unroll
            for (int tn = 0; tn < 4; ++tn) aq[i][tn] = zero;
        #pragma unroll
        for (int kc = 0; kc < 4; ++kc) {
            bf16x8 xq[4];
            #pragma unroll
            for (int tn = 0; tn < 4; ++tn)
                xq[tn] = *(const bf16x8*)&xs[ao_off(16 * tn + cn, 8 * g + 32 * kc)];
            #pragma unroll
            for (int i = 0; i < 2; ++i)
                #pragma unroll
                for (int tn = 0; tn < 4; ++tn)
                    aq[i][tn] = MFMA32(wqf[i][kc], xq[tn], aq[i][tn]);   // D[d'][tok]
        }
        const float4 b0 = *(const float4*)&qkv_b[32 * h + 8 * g];      // i=0 (d-permuted)
        const float4 b1 = *(const float4*)&qkv_b[32 * h + 8 * g + 4];  // i=1
        #pragma unroll
        for (int tn = 0; tn < 4; ++tn) {
            f32x4 q0 = aq[0][tn], q1 = aq[1][tn];
            qb[tn] = cat8(pack4bf(q0[0] + b0.x, q0[1] + b0.y, q0[2] + b0.z, q0[3] + b0.w),
                          pack4bf(q1[0] + b1.x, q1[1] + b1.y, q1[2] + b1.z, q1[3] + b1.w));
        }
    }

    // ---- QKV pass 2: K + V MERGED (sigma-permuted x rows read ONCE) ----
    {
        f32x4 ak[2][4], av[4][2];
        #pragma unroll
        for (int i = 0; i < 2; ++i)
            #pragma unroll
            for (int tn = 0; tn < 4; ++tn) { ak[i][tn] = zero; av[tn][i] = zero; }
        #pragma unroll
        for (int kc = 0; kc < 4; ++kc) {
            bf16x8 xkv[4];
            #pragma unroll
            for (int tn = 0; tn < 4; ++tn) {
                const int row = 32 * (tn >> 1) + 8 * (cn >> 2) + 4 * (tn & 1) + (cn & 3);
                xkv[tn] = *(const bf16x8*)&xs[ao_off(row, 8 * g + 32 * kc)];
            }
            #pragma unroll
            for (int i = 0; i < 2; ++i) {
                const bf16x8 wk = *(const bf16x8*)&wq_bf[16384 + (h * 2 + i) * 2048 + kc * 512 + lane32];
                const bf16x8 wv = *(const bf16x8*)&wq_bf[32768 + (h * 2 + i) * 2048 + kc * 512 + lane32];
                #pragma unroll
                for (int tn = 0; tn < 4; ++tn) {
                    ak[i][tn] = MFMA32(wk, xkv[tn], ak[i][tn]);   // D[d'][tok-slot]
                    av[tn][i] = MFMA32(xkv[tn], wv, av[tn][i]);   // D[tok-slot][d]
                }
            }
        }
        const float4 b0 = *(const float4*)&qkv_b[128 + 32 * h + 8 * g];
        const float4 b1 = *(const float4*)&qkv_b[128 + 32 * h + 8 * g + 4];
        #pragma unroll
        for (int tn = 0; tn < 4; ++tn) {
            f32x4 k0 = ak[0][tn], k1 = ak[1][tn];
            kb[tn] = cat8(pack4bf(k0[0] + b0.x, k0[1] + b0.y, k0[2] + b0.z, k0[3] + b0.w),
                          pack4bf(k1[0] + b1.x, k1[1] + b1.y, k1[2] + b1.z, k1[3] + b1.w));
        }
        uint2 vb2[4][2];
        #pragma unroll
        for (int i = 0; i < 2; ++i) {
            const float bv = qkv_b[256 + 32 * h + 16 * i + cn];
            #pragma unroll
            for (int tn = 0; tn < 4; ++tn) {
                f32x4 v4 = av[tn][i];
                vb2[tn][i] = pack4bf(v4[0] + bv, v4[1] + bv, v4[2] + bv, v4[3] + bv);
            }
        }
        #pragma unroll
        for (int kk = 0; kk < 2; ++kk)
            #pragma unroll
            for (int ta = 0; ta < 2; ++ta)
                vA[kk][ta] = cat8(vb2[2 * kk][ta], vb2[2 * kk + 1][ta]);
    }

    // HOIST 2: all-tj bias loads (independent of QK^T results)
    uint4 bb[4][2];
    #pragma unroll
    for (int tj = 0; tj < 4; ++tj) {
        const ushort* bp = biasb + (((h * 64 + 16 * tj + cn) * 4 + g) << 4);
        bb[tj][0] = *(const uint4*)bp;
        bb[tj][1] = *(const uint4*)(bp + 8);
    }

    // ---- attention per tj: QK^T -> softmax -> PV (minimal live set) ----
    const float SCALE2 = 0.17677669529663687f * 1.4426950408889634f;  // scale*log2(e)
    #pragma unroll
    for (int tj = 0; tj < 4; ++tj) {
        f32x4 s[4];
        #pragma unroll
        for (int ti = 0; ti < 4; ++ti)
            s[ti] = MFMA32(kb[ti], qb[tj], zero);          // S D[slot][nq], K=32 over d

        float sum = 0.f;
        uint2 pkt[4];
        #pragma unroll
        for (int ti = 0; ti < 4; ++ti) {
            const uint4 q4 = bb[tj][ti >> 1];
            const unsigned w0 = (ti & 1) ? q4.z : q4.x;
            const unsigned w1 = (ti & 1) ? q4.w : q4.y;
            const float b0 = __uint_as_float(w0 << 16);
            const float b1 = __uint_as_float(w0 & 0xffff0000u);
            const float b2 = __uint_as_float(w1 << 16);
            const float b3 = __uint_as_float(w1 & 0xffff0000u);
            f32x4 sv = s[ti];
            sv[0] = exp2f(fmaf(sv[0], SCALE2, b0));
            sv[1] = exp2f(fmaf(sv[1], SCALE2, b1));
            sv[2] = exp2f(fmaf(sv[2], SCALE2, b2));
            sv[3] = exp2f(fmaf(sv[3], SCALE2, b3));
            pkt[ti] = pack4bf(sv[0], sv[1], sv[2], sv[3]);   // = PV B-frag piece
            sum += (sv[0] + sv[1]) + (sv[2] + sv[3]);
        }
        sum += __shfl_xor(sum, 16, 64);
        sum += __shfl_xor(sum, 32, 64);
        const float rs = 1.0f / sum;                         // lane-local

        const bf16x8 p0 = cat8(pkt[0], pkt[1]);   // B-frag, tokens 0..31
        const bf16x8 p1 = cat8(pkt[2], pkt[3]);   // B-frag, tokens 32..63
        #pragma unroll
        for (int ta = 0; ta < 2; ++ta) {
            f32x4 o = MFMA32(vA[0][ta], p0, zero);
            o = MFMA32(vA[1][ta], p1, o);                    // D[d][nq]
            *(uint2*)&aoL[ao_off(16 * tj + cn, 32 * h + 16 * ta + 4 * g)] =
                pack4bf(o[0] * rs, o[1] * rs, o[2] * rs, o[3] * rs);
        }
    }

    // HOIST 3: proj weight fragments (independent of ao) before barrier 2
    bf16x8 wpf[2][4];
    #pragma unroll
    for (int i = 0; i < 2; ++i)
        #pragma unroll
        for (int kc = 0; kc < 4; ++kc)
            wpf[i][kc] = *(const bf16x8*)&wp_bf[(2 * h + i) * 2048 + kc * 512 + lane32];

    __syncthreads();                              // (2) ao ready (wpf drained here too)

    // ---- out projection: aof read ONCE per kc; weights already in regs ----
    float* og = out + w * 8192;
    {
        f32x4 po[2][4];
        #pragma unroll
        for (int i = 0; i < 2; ++i)
            #pragma unroll
            for (int tj = 0; tj < 4; ++tj) po[i][tj] = zero;
        #pragma unroll
        for (int kc = 0; kc < 4; ++kc) {
            bf16x8 aof[4];
            #pragma unroll
            for (int tj = 0; tj < 4; ++tj)
                aof[tj] = *(const bf16x8*)&aoL[ao_off(16 * tj + cn, 8 * g + 32 * kc)];
            #pragma unroll
            for (int i = 0; i < 2; ++i)
                #pragma unroll
                for (int tj = 0; tj < 4; ++tj)
                    po[i][tj] = MFMA32(wpf[i][kc], aof[tj], po[i][tj]);
        }
        #pragma unroll
        for (int i = 0; i < 2; ++i) {
            const int co0 = 16 * (2 * h + i) + 4 * g;
            const float4 pb4 = *(const float4*)&proj_b[co0];
            #pragma unroll
            for (int tj = 0; tj < 4; ++tj) {
                f32x4 pv = po[i][tj];
                float4 ov;
                ov.x = pv[0] + pb4.x; ov.y = pv[1] + pb4.y;
                ov.z = pv[2] + pb4.z; ov.w = pv[3] + pb4.w;
                *(float4*)&og[(16 * tj + cn) * 128 + co0] = ov;
            }
        }
    }
}

extern "C" void kernel_launch(void* const* d_in, const int* in_sizes, int n_in,
                              void* d_out, int out_size, void* d_ws, size_t ws_size,
                              hipStream_t stream) {
    const float* x          = (const float*)d_in[0];
    const float* qkv_w      = (const float*)d_in[1];
    const float* qkv_b      = (const float*)d_in[2];
    const float* proj_w     = (const float*)d_in[3];
    const float* proj_b     = (const float*)d_in[4];
    const float* bias_table = (const float*)d_in[5];
    float* out = (float*)d_out;

    // ws layout: [0,98304) wq_bf fragment-major | [98304,131072) wp_bf fragment-major
    //            [131072,163840) biasb bf16 (nk sigma-permuted)
    ushort* wq_bf = (ushort*)d_ws;
    ushort* wp_bf = (ushort*)((char*)d_ws + 98304);
    ushort* biasb = (ushort*)((char*)d_ws + 131072);

    prep_kernel<<<dim3(192), dim3(256), 0, stream>>>(qkv_w, proj_w, bias_table, wq_bf, wp_bf, biasb);
    winattn_mfma<<<dim3(4096), dim3(256), 0, stream>>>(x, qkv_b, proj_b, wq_bf, wp_bf, biasb, out);
}